// Round 6
// baseline (144.543 us; speedup 1.0000x reference)
//
#include <hip/hip_runtime.h>
#include <math.h>

// B=32, T=256, C=128, NEIGH=5, TOPK=4.
// proj:  pf=norm(x@Wpf^T) -> split bf16; ns=norm(x@Wns^T) -> split + fp32; v=x@Wv^T fp32
// prep:  role Q: Q=sc*sum_n v_ns[n]*ns[inxs] -> split;  role VT: vt[c][t]=v[t][c] -> split
// gram:  MFMA from global split arrays (no LDS): G=pf@pf^T, S=Q@ns^T
// fused: rowmax(G) conv + S + mask -> softmax -> PV via split-bf16 MFMA (out^T tiles)

#define TT 256
#define CC 128

using bf16x8 = __attribute__((ext_vector_type(8))) short;
using f32x4  = __attribute__((ext_vector_type(4))) float;

__device__ __forceinline__ short bf_hi(float x) {
    unsigned u = __float_as_uint(x);
    return (short)((u + 0x7FFFu + ((u >> 16) & 1u)) >> 16);
}
__device__ __forceinline__ void bf_split(float x, short& h, short& l) {
    h = bf_hi(x);
    float hf = __uint_as_float(((unsigned)(unsigned short)h) << 16);
    l = bf_hi(x - hf);
}
__device__ __forceinline__ float max5(float a, float b, float c, float d, float e) {
    return fmaxf(fmaxf(fmaxf(a, b), fmaxf(c, d)), e);
}

// ---- proj: 64 rows/block, one matrix per blockIdx.y.
__global__ __launch_bounds__(256) void proj_kernel(
    const float* __restrict__ x,
    const float* __restrict__ W0, const float* __restrict__ W1, const float* __restrict__ W2,
    short* __restrict__ pf_h, short* __restrict__ pf_l,
    short* __restrict__ ns_h, short* __restrict__ ns_l,
    float* __restrict__ ns_f, float* __restrict__ v_f)
{
    __shared__ float xs[64][36];
    __shared__ float Ws[128][36];
    const int tid = threadIdx.x, ty = tid >> 4, tx = tid & 15;
    const int row0 = blockIdx.x * 64;
    const int m = blockIdx.y;
    const float* __restrict__ W = (m == 0) ? W0 : (m == 1) ? W1 : W2;
    float acc[4][8] = {};

    for (int k0 = 0; k0 < CC; k0 += 32) {
        __syncthreads();
        for (int i = 0; i < 2; i++) {
            int flat = i * 256 + tid, r = flat >> 3, q = (flat & 7) * 4;
            *(float4*)&xs[r][q] = *(const float4*)&x[(row0 + r) * CC + k0 + q];
        }
        for (int i = 0; i < 4; i++) {
            int flat = i * 256 + tid, r = flat >> 3, q = (flat & 7) * 4;
            *(float4*)&Ws[r][q] = *(const float4*)&W[r * CC + k0 + q];
        }
        __syncthreads();
        for (int kq = 0; kq < 32; kq += 4) {
            float4 av[4], bv[8];
            for (int u = 0; u < 4; u++) av[u] = *(float4*)&xs[ty + 16 * u][kq];
            for (int w = 0; w < 8; w++) bv[w] = *(float4*)&Ws[tx + 16 * w][kq];
            for (int u = 0; u < 4; u++)
                for (int w = 0; w < 8; w++) {
                    acc[u][w] = fmaf(av[u].x, bv[w].x, acc[u][w]);
                    acc[u][w] = fmaf(av[u].y, bv[w].y, acc[u][w]);
                    acc[u][w] = fmaf(av[u].z, bv[w].z, acc[u][w]);
                    acc[u][w] = fmaf(av[u].w, bv[w].w, acc[u][w]);
                }
        }
    }
    for (int u = 0; u < 4; u++) {
        int row = row0 + ty + 16 * u;
        if (m == 2) {
            for (int w = 0; w < 8; w++) v_f[row * CC + tx + 16 * w] = acc[u][w];
        } else {
            float ss = 0.f;
            for (int w = 0; w < 8; w++) ss += acc[u][w] * acc[u][w];
            for (int off = 8; off; off >>= 1) ss += __shfl_xor(ss, off);
            float inv = 1.f / fmaxf(sqrtf(ss), 1e-12f);
            for (int w = 0; w < 8; w++) {
                float v = acc[u][w] * inv;
                short h, l;
                bf_split(v, h, l);
                int idx = row * CC + tx + 16 * w;
                if (m == 0) { pf_h[idx] = h; pf_l[idx] = l; }
                else        { ns_h[idx] = h; ns_l[idx] = l; ns_f[idx] = v; }
            }
        }
    }
}

// ---- prep: blocks [0,512): Q gather+split; [512,640): v transpose+split.
__global__ __launch_bounds__(256) void prep_kernel(
    const float* __restrict__ ns_f, const int* __restrict__ inxs,
    const float* __restrict__ v_ns, const float* __restrict__ g_ns,
    const float* __restrict__ v_f,
    short* __restrict__ q_h, short* __restrict__ q_l,
    short* __restrict__ vt_h, short* __restrict__ vt_l)
{
    __shared__ float Ls[64][132];
    const int bx = blockIdx.x, tid = threadIdx.x;
    if (bx < 512) {
        float n2 = v_ns[0]*v_ns[0] + v_ns[1]*v_ns[1] + v_ns[2]*v_ns[2] + v_ns[3]*v_ns[3];
        float sc = g_ns[0] / sqrtf(n2);
        const float w0 = sc*v_ns[0], w1 = sc*v_ns[1], w2 = sc*v_ns[2], w3 = sc*v_ns[3];
        for (int it = 0; it < 2; it++) {
            int t4 = bx * 512 + it * 256 + tid;         // 262144 f4-tasks
            int q = (t4 & 31) * 4, gr = t4 >> 5;        // gr: global row 0..8191
            int b = gr >> 8;
            int4 id = *(const int4*)&inxs[gr * 4];
            const float* Nb = ns_f + (size_t)b * TT * CC;
            float4 aa = *(const float4*)&Nb[id.x * CC + q];
            float4 ab = *(const float4*)&Nb[id.y * CC + q];
            float4 ac = *(const float4*)&Nb[id.z * CC + q];
            float4 ad = *(const float4*)&Nb[id.w * CC + q];
            float4 r4;
            r4.x = w0*aa.x + w1*ab.x + w2*ac.x + w3*ad.x;
            r4.y = w0*aa.y + w1*ab.y + w2*ac.y + w3*ad.y;
            r4.z = w0*aa.z + w1*ab.z + w2*ac.z + w3*ad.z;
            r4.w = w0*aa.w + w1*ab.w + w2*ac.w + w3*ad.w;
            short4 h4, l4;
            bf_split(r4.x, h4.x, l4.x); bf_split(r4.y, h4.y, l4.y);
            bf_split(r4.z, h4.z, l4.z); bf_split(r4.w, h4.w, l4.w);
            *(short4*)&q_h[(size_t)gr * CC + q] = h4;
            *(short4*)&q_l[(size_t)gr * CC + q] = l4;
        }
    } else {
        int blk = bx - 512;
        int b = blk >> 2, t0 = (blk & 3) * 64;
        const float* Vb = v_f + (size_t)b * TT * CC;
        for (int i = 0; i < 8; i++) {
            int flat = i * 256 + tid, r = flat >> 5, cq = (flat & 31) * 4;
            *(float4*)&Ls[r][cq] = *(const float4*)&Vb[(t0 + r) * CC + cq];
        }
        __syncthreads();
        int c = tid & 127, th = tid >> 7;
        for (int j = 0; j < 8; j++) {
            short4 h4, l4;
            for (int e = 0; e < 4; e++) {
                float v = Ls[th * 32 + j * 4 + e][c];
                bf_split(v, ((short*)&h4)[e], ((short*)&l4)[e]);
            }
            size_t o = ((size_t)b * CC + c) * TT + t0 + th * 32 + j * 4;
            *(short4*)&vt_h[o] = h4;
            *(short4*)&vt_l[o] = l4;
        }
    }
}

// ---- gram: LDS-free MFMA from pre-split global arrays. z = b*2 + half.
__global__ __launch_bounds__(256) void gram_mfma(
    const short* __restrict__ pf_h, const short* __restrict__ pf_l,
    const short* __restrict__ ns_h, const short* __restrict__ ns_l,
    const short* __restrict__ q_h,  const short* __restrict__ q_l,
    float* __restrict__ G, float* __restrict__ S)
{
    const int tid = threadIdx.x;
    const int m0 = blockIdx.x * 64, n0 = blockIdx.y * 64;
    const int b = blockIdx.z >> 1, half = blockIdx.z & 1;
    const size_t base = (size_t)b * TT * CC;
    const short* __restrict__ Ahp = (half ? q_h : pf_h) + base;
    const short* __restrict__ Alp = (half ? q_l : pf_l) + base;
    const short* __restrict__ Bhp = (half ? ns_h : pf_h) + base;
    const short* __restrict__ Blp = (half ? ns_l : pf_l) + base;
    const int lane = tid & 63, wave = tid >> 6;
    const int wm = wave >> 1, wn = wave & 1;
    const int quad = lane >> 4, lr = lane & 15;
    const int am0 = (m0 + 32 * wm + lr) * CC, am1 = am0 + 16 * CC;
    const int bn0 = (n0 + 32 * wn + lr) * CC, bn1 = bn0 + 16 * CC;
    f32x4 z4 = {0.f, 0.f, 0.f, 0.f};
    f32x4 acc[2][2] = {{z4, z4}, {z4, z4}};
    #pragma unroll
    for (int k0 = 0; k0 < CC; k0 += 32) {
        int ko = k0 + quad * 8;
        bf16x8 a0h = *(const bf16x8*)&Ahp[am0 + ko];
        bf16x8 a0l = *(const bf16x8*)&Alp[am0 + ko];
        bf16x8 a1h = *(const bf16x8*)&Ahp[am1 + ko];
        bf16x8 a1l = *(const bf16x8*)&Alp[am1 + ko];
        bf16x8 b0h = *(const bf16x8*)&Bhp[bn0 + ko];
        bf16x8 b0l = *(const bf16x8*)&Blp[bn0 + ko];
        bf16x8 b1h = *(const bf16x8*)&Bhp[bn1 + ko];
        bf16x8 b1l = *(const bf16x8*)&Blp[bn1 + ko];
        acc[0][0] = __builtin_amdgcn_mfma_f32_16x16x32_bf16(a0h, b0h, acc[0][0], 0, 0, 0);
        acc[0][0] = __builtin_amdgcn_mfma_f32_16x16x32_bf16(a0h, b0l, acc[0][0], 0, 0, 0);
        acc[0][0] = __builtin_amdgcn_mfma_f32_16x16x32_bf16(a0l, b0h, acc[0][0], 0, 0, 0);
        acc[0][1] = __builtin_amdgcn_mfma_f32_16x16x32_bf16(a0h, b1h, acc[0][1], 0, 0, 0);
        acc[0][1] = __builtin_amdgcn_mfma_f32_16x16x32_bf16(a0h, b1l, acc[0][1], 0, 0, 0);
        acc[0][1] = __builtin_amdgcn_mfma_f32_16x16x32_bf16(a0l, b1h, acc[0][1], 0, 0, 0);
        acc[1][0] = __builtin_amdgcn_mfma_f32_16x16x32_bf16(a1h, b0h, acc[1][0], 0, 0, 0);
        acc[1][0] = __builtin_amdgcn_mfma_f32_16x16x32_bf16(a1h, b0l, acc[1][0], 0, 0, 0);
        acc[1][0] = __builtin_amdgcn_mfma_f32_16x16x32_bf16(a1l, b0h, acc[1][0], 0, 0, 0);
        acc[1][1] = __builtin_amdgcn_mfma_f32_16x16x32_bf16(a1h, b1h, acc[1][1], 0, 0, 0);
        acc[1][1] = __builtin_amdgcn_mfma_f32_16x16x32_bf16(a1h, b1l, acc[1][1], 0, 0, 0);
        acc[1][1] = __builtin_amdgcn_mfma_f32_16x16x32_bf16(a1l, b1h, acc[1][1], 0, 0, 0);
    }
    float* __restrict__ Cb = (half ? S : G) + (size_t)b * TT * TT;
    for (int tm = 0; tm < 2; tm++)
        for (int tn = 0; tn < 2; tn++) {
            int rb = m0 + 32 * wm + 16 * tm + quad * 4;
            int cb = n0 + 32 * wn + 16 * tn + lr;
            for (int reg = 0; reg < 4; reg++)
                Cb[(size_t)(rb + reg) * TT + cb] = acc[tm][tn][reg];
        }
}

// ---- fused: rowmax conv + S + mask -> softmax -> PV via split-bf16 MFMA.
__global__ __launch_bounds__(256, 2) void fused_smax_pv(
    const float* __restrict__ G, const float* __restrict__ S,
    const int* __restrict__ radj, const float* __restrict__ v_pf,
    const float* __restrict__ g_pf,
    const short* __restrict__ vt_h, const short* __restrict__ vt_l,
    float* __restrict__ out)
{
    __shared__ float Gs[20 * 256];
    __shared__ float RM[20 * 256];
    __shared__ short ATH[16 * 264];
    __shared__ short ATL[16 * 264];
    __shared__ float RD[64];
    __shared__ float RMX[64];
    const int tid = threadIdx.x;
    const int xt = blockIdx.x, b = blockIdx.y;
    const int x0 = xt * 16;
    const int rbase = min(max(x0 - 2, 0), TT - 5);
    for (int i = 0; i < 5; i++) {
        int flat = i * 256 + tid, ri = flat >> 6, q = (flat & 63) * 4;
        int r = min(rbase + ri, TT - 1);
        *(float4*)&Gs[ri * 256 + q] = *(const float4*)&G[(size_t)b * TT * TT + r * TT + q];
    }
    float n2 = 0.f;
    for (int i = 0; i < 5; i++) n2 += v_pf[i] * v_pf[i];
    float sc = g_pf[0] / sqrtf(n2);
    float wpf[5];
    for (int i = 0; i < 5; i++) wpf[i] = sc * v_pf[i];
    __syncthreads();
    // windowed row-max, vectorized: 1280 tasks of 4 cols
    for (int t = 0; t < 5; t++) {
        int task = t * 256 + tid;
        int i = task >> 6, g = task & 63;
        const float* row = &Gs[i * 256];
        float4 X = *(float4*)&row[4 * g];
        float m0_, m1_, m2_, m3_;
        if (g == 0) {
            float4 N = *(float4*)&row[4];
            float mx = fmaxf(fmaxf(X.x, X.y), fmaxf(X.z, X.w));
            m0_ = m1_ = m2_ = fmaxf(mx, N.x);
            m3_ = max5(X.y, X.z, X.w, N.x, N.y);
        } else if (g == 63) {
            float4 P = *(float4*)&row[248];
            m0_ = max5(P.z, P.w, X.x, X.y, X.z);
            float mx = fmaxf(fmaxf(X.x, X.y), fmaxf(X.z, X.w));
            m1_ = m2_ = m3_ = fmaxf(P.w, mx);
        } else {
            float4 P = *(float4*)&row[4 * g - 4];
            float4 N = *(float4*)&row[4 * g + 4];
            m0_ = max5(P.z, P.w, X.x, X.y, X.z);
            m1_ = max5(P.w, X.x, X.y, X.z, X.w);
            m2_ = max5(X.x, X.y, X.z, X.w, N.x);
            m3_ = max5(X.y, X.z, X.w, N.x, N.y);
        }
        float4 o4 = {m0_, m1_, m2_, m3_};
        *(float4*)&RM[i * 256 + 4 * g] = o4;
    }
    __syncthreads();
    const int y = tid;
    const size_t sb = (size_t)b * TT * TT;
    float lv[16];
    if (xt > 0 && xt < 15) {            // interior: no clipping, conv in registers
        float rm[20];
        #pragma unroll
        for (int r = 0; r < 20; r++) rm[r] = RM[r * 256 + y];
        #pragma unroll
        for (int xi = 0; xi < 16; xi++) {
            float s = wpf[0] * rm[xi];
            #pragma unroll
            for (int i = 1; i < 5; i++) s = fmaf(wpf[i], rm[xi + i], s);
            lv[xi] = s;
        }
    } else {
        for (int xi = 0; xi < 16; xi++) {
            int sxr = min(max(x0 + xi - 2, 0), TT - 5) - rbase;
            float s = 0.f;
            for (int i = 0; i < 5; i++) s = fmaf(wpf[i], RM[(sxr + i) * 256 + y], s);
            lv[xi] = s;
        }
    }
    for (int xi = 0; xi < 16; xi++) {
        lv[xi] += S[sb + (x0 + xi) * TT + y];
        if (radj[sb + (x0 + xi) * TT + y] == 0) lv[xi] += -1e22f;
    }
    const int lane = tid & 63, wv = tid >> 6;
    for (int xi = 0; xi < 16; xi++) {
        float v = lv[xi];
        for (int o = 32; o; o >>= 1) v = fmaxf(v, __shfl_xor(v, o));
        if (lane == 0) RMX[xi * 4 + wv] = v;
    }
    __syncthreads();
    for (int xi = 0; xi < 16; xi++) {
        float mx = fmaxf(fmaxf(RMX[xi * 4], RMX[xi * 4 + 1]),
                         fmaxf(RMX[xi * 4 + 2], RMX[xi * 4 + 3]));
        float e = __expf(lv[xi] - mx);
        short h, l;
        bf_split(e, h, l);
        ATH[xi * 264 + y] = h;
        ATL[xi * 264 + y] = l;
        for (int o = 32; o; o >>= 1) e += __shfl_xor(e, o);
        if (lane == 0) RD[xi * 4 + wv] = e;
    }
    __syncthreads();
    // PV: out^T[c,q] tiles. A = vt (global, split), B = attn (LDS, split).
    const int quad = lane >> 4, lr = lane & 15;
    const int c0 = wv * 32;
    const short* __restrict__ vhb = vt_h + (size_t)b * CC * TT;
    const short* __restrict__ vlb = vt_l + (size_t)b * CC * TT;
    const int ar0 = (c0 + lr) * TT, ar1 = ar0 + 16 * TT;
    f32x4 z4 = {0.f, 0.f, 0.f, 0.f};
    f32x4 acc[2] = {z4, z4};
    #pragma unroll
    for (int k0 = 0; k0 < TT; k0 += 32) {
        int ko = k0 + quad * 8;
        bf16x8 bh = *(bf16x8*)&ATH[lr * 264 + ko];
        bf16x8 bl = *(bf16x8*)&ATL[lr * 264 + ko];
        bf16x8 a0h = *(const bf16x8*)&vhb[ar0 + ko];
        bf16x8 a0l = *(const bf16x8*)&vlb[ar0 + ko];
        bf16x8 a1h = *(const bf16x8*)&vhb[ar1 + ko];
        bf16x8 a1l = *(const bf16x8*)&vlb[ar1 + ko];
        acc[0] = __builtin_amdgcn_mfma_f32_16x16x32_bf16(a0h, bh, acc[0], 0, 0, 0);
        acc[0] = __builtin_amdgcn_mfma_f32_16x16x32_bf16(a0h, bl, acc[0], 0, 0, 0);
        acc[0] = __builtin_amdgcn_mfma_f32_16x16x32_bf16(a0l, bh, acc[0], 0, 0, 0);
        acc[1] = __builtin_amdgcn_mfma_f32_16x16x32_bf16(a1h, bh, acc[1], 0, 0, 0);
        acc[1] = __builtin_amdgcn_mfma_f32_16x16x32_bf16(a1h, bl, acc[1], 0, 0, 0);
        acc[1] = __builtin_amdgcn_mfma_f32_16x16x32_bf16(a1l, bh, acc[1], 0, 0, 0);
    }
    float sm = RD[lr * 4] + RD[lr * 4 + 1] + RD[lr * 4 + 2] + RD[lr * 4 + 3];
    float rinv = 1.f / sm;
    for (int tm = 0; tm < 2; tm++) {
        float4 r;
        r.x = acc[tm][0] * rinv; r.y = acc[tm][1] * rinv;
        r.z = acc[tm][2] * rinv; r.w = acc[tm][3] * rinv;
        *(float4*)&out[(size_t)b * TT * CC + (x0 + lr) * CC + c0 + 16 * tm + quad * 4] = r;
    }
}

extern "C" void kernel_launch(void* const* d_in, const int* in_sizes, int n_in,
                              void* d_out, int out_size, void* d_ws, size_t ws_size,
                              hipStream_t stream) {
    const float* x    = (const float*)d_in[0];
    const int*   radj = (const int*)d_in[1];
    const int*   inxs = (const int*)d_in[2];
    const float* Wpf  = (const float*)d_in[3];
    const float* Wns  = (const float*)d_in[4];
    const float* Wv   = (const float*)d_in[5];
    const float* v_pf = (const float*)d_in[6];
    const float* g_pf = (const float*)d_in[7];
    const float* v_ns = (const float*)d_in[8];
    const float* g_ns = (const float*)d_in[9];
    float* out = (float*)d_out;

    char* base = (char*)d_ws;
    float* ns_f = (float*)(base);                    // 4MB
    float* v_f  = (float*)(base + (4u << 20));       // 4MB
    short* pf_h = (short*)(base + (8u << 20));       // 2MB each below
    short* pf_l = (short*)(base + (10u << 20));
    short* ns_h = (short*)(base + (12u << 20));
    short* ns_l = (short*)(base + (14u << 20));
    short* q_h  = (short*)(base + (16u << 20));
    short* q_l  = (short*)(base + (18u << 20));
    short* vt_h = (short*)(base + (20u << 20));
    short* vt_l = (short*)(base + (22u << 20));
    float* G    = (float*)(base + (24u << 20));      // 8MB
    float* S    = (float*)(base + (32u << 20));      // 8MB

    proj_kernel<<<dim3(128, 3), 256, 0, stream>>>(x, Wpf, Wns, Wv,
                                                  pf_h, pf_l, ns_h, ns_l, ns_f, v_f);
    prep_kernel<<<640, 256, 0, stream>>>(ns_f, inxs, v_ns, g_ns, v_f,
                                         q_h, q_l, vt_h, vt_l);
    gram_mfma<<<dim3(4, 4, 64), 256, 0, stream>>>(pf_h, pf_l, ns_h, ns_l, q_h, q_l, G, S);
    fused_smax_pv<<<dim3(16, 32), 256, 0, stream>>>(G, S, radj, v_pf, g_pf,
                                                    vt_h, vt_l, out);
}

// Round 7
// 126.647 us; speedup vs baseline: 1.1413x; 1.1413x over previous
//
#include <hip/hip_runtime.h>
#include <math.h>

// B=32, T=256, C=128, NEIGH=5, TOPK=4.
// proj (MFMA, split-bf16): pf=norm(x@Wpf^T), ns=norm(x@Wns^T) -> fp32;
//                          v=x@Wv^T -> stored transposed split bf16 vt[c][t]
// gram (R5, proven): G[b]=pf@pf^T ; S[b]=Q@ns^T (Q gathered on the fly), split-bf16 MFMA
// fused: vectorized rowmax(G) conv + S + mask -> softmax -> PV via split-bf16 MFMA (vt)

#define TT 256
#define CC 128

using bf16x8 = __attribute__((ext_vector_type(8))) short;
using f32x4  = __attribute__((ext_vector_type(4))) float;

__device__ __forceinline__ short bf_hi(float x) {
    unsigned u = __float_as_uint(x);
    return (short)((u + 0x7FFFu + ((u >> 16) & 1u)) >> 16);
}
__device__ __forceinline__ void bf_split(float x, short& h, short& l) {
    h = bf_hi(x);
    float hf = __uint_as_float(((unsigned)(unsigned short)h) << 16);
    l = bf_hi(x - hf);
}
__device__ __forceinline__ float max5(float a, float b, float c, float d, float e) {
    return fmaxf(fmaxf(fmaxf(a, b), fmaxf(c, d)), e);
}

// ---- proj: 32 rows/block, one matrix per blockIdx.y, split-bf16 MFMA.
// wave wn owns 32 output cols; all waves cover all 32 rows.
__global__ __launch_bounds__(256, 4) void proj_kernel(
    const float* __restrict__ x,
    const float* __restrict__ W0, const float* __restrict__ W1, const float* __restrict__ W2,
    float* __restrict__ pf, float* __restrict__ ns,
    short* __restrict__ vt_h, short* __restrict__ vt_l)
{
    __shared__ short Ah[32 * 40], Al[32 * 40];
    __shared__ short Bh[128 * 40], Bl[128 * 40];
    __shared__ float ssb[32][4];
    const int tid = threadIdx.x;
    const int row0 = blockIdx.x * 32;
    const int m = blockIdx.y;
    const float* __restrict__ W = (m == 0) ? W0 : (m == 1) ? W1 : W2;
    const int lane = tid & 63, wn = tid >> 6;
    const int quad = lane >> 4, lr = lane & 15;
    f32x4 z4 = {0.f, 0.f, 0.f, 0.f};
    f32x4 acc[2][2] = {{z4, z4}, {z4, z4}};   // [ra: row-16-tile][tn: col-16-tile]

    for (int k0 = 0; k0 < CC; k0 += 32) {
        __syncthreads();
        {   // x tile: 32x32 = 256 float4
            int r = tid >> 3, q = (tid & 7) * 4;
            float4 a4 = *(const float4*)&x[(row0 + r) * CC + k0 + q];
            short4 h4, l4;
            bf_split(a4.x, h4.x, l4.x); bf_split(a4.y, h4.y, l4.y);
            bf_split(a4.z, h4.z, l4.z); bf_split(a4.w, h4.w, l4.w);
            *(short4*)&Ah[r * 40 + q] = h4; *(short4*)&Al[r * 40 + q] = l4;
        }
        for (int i = 0; i < 4; i++) {  // W tile: 128x32 = 1024 float4
            int flat = i * 256 + tid, r = flat >> 3, q = (flat & 7) * 4;
            float4 b4 = *(const float4*)&W[r * CC + k0 + q];
            short4 h4, l4;
            bf_split(b4.x, h4.x, l4.x); bf_split(b4.y, h4.y, l4.y);
            bf_split(b4.z, h4.z, l4.z); bf_split(b4.w, h4.w, l4.w);
            *(short4*)&Bh[r * 40 + q] = h4; *(short4*)&Bl[r * 40 + q] = l4;
        }
        __syncthreads();
        bf16x8 ah[2], al[2], bh[2], bl[2];
        for (int ra = 0; ra < 2; ra++) {
            int ar = (16 * ra + lr) * 40 + quad * 8;
            ah[ra] = *(bf16x8*)&Ah[ar];
            al[ra] = *(bf16x8*)&Al[ar];
        }
        for (int tn = 0; tn < 2; tn++) {
            int br = (32 * wn + 16 * tn + lr) * 40 + quad * 8;
            bh[tn] = *(bf16x8*)&Bh[br];
            bl[tn] = *(bf16x8*)&Bl[br];
        }
        for (int ra = 0; ra < 2; ra++)
            for (int tn = 0; tn < 2; tn++) {
                acc[ra][tn] = __builtin_amdgcn_mfma_f32_16x16x32_bf16(ah[ra], bh[tn], acc[ra][tn], 0, 0, 0);
                acc[ra][tn] = __builtin_amdgcn_mfma_f32_16x16x32_bf16(ah[ra], bl[tn], acc[ra][tn], 0, 0, 0);
                acc[ra][tn] = __builtin_amdgcn_mfma_f32_16x16x32_bf16(al[ra], bh[tn], acc[ra][tn], 0, 0, 0);
            }
    }
    // D layout: row(m) = 16ra + quad*4 + reg, col(n) = 32wn + 16tn + lr
    if (m < 2) {
        float* __restrict__ o = (m == 0) ? pf : ns;
        float ssp[2][4];
        for (int ra = 0; ra < 2; ra++)
            for (int reg = 0; reg < 4; reg++) {
                float s = acc[ra][0][reg] * acc[ra][0][reg]
                        + acc[ra][1][reg] * acc[ra][1][reg];
                for (int off = 1; off < 16; off <<= 1) s += __shfl_xor(s, off);
                ssp[ra][reg] = s;
            }
        if (lr == 0)
            for (int ra = 0; ra < 2; ra++)
                for (int reg = 0; reg < 4; reg++)
                    ssb[16 * ra + quad * 4 + reg][wn] = ssp[ra][reg];
        __syncthreads();
        for (int ra = 0; ra < 2; ra++)
            for (int reg = 0; reg < 4; reg++) {
                int ml = 16 * ra + quad * 4 + reg;
                float ss = ssb[ml][0] + ssb[ml][1] + ssb[ml][2] + ssb[ml][3];
                float inv = 1.f / fmaxf(sqrtf(ss), 1e-12f);
                int row = row0 + ml;
                for (int tn = 0; tn < 2; tn++)
                    o[row * CC + 32 * wn + 16 * tn + lr] = acc[ra][tn][reg] * inv;
            }
    } else {
        // v: store transposed split bf16: vt[b][c][t], 4 consecutive t per short4
        for (int ra = 0; ra < 2; ra++) {
            int rowbase = row0 + 16 * ra + quad * 4;
            int b = rowbase >> 8, t0 = rowbase & 255;
            for (int tn = 0; tn < 2; tn++) {
                int c = 32 * wn + 16 * tn + lr;
                short4 h4, l4;
                for (int reg = 0; reg < 4; reg++)
                    bf_split(acc[ra][tn][reg], ((short*)&h4)[reg], ((short*)&l4)[reg]);
                size_t o = ((size_t)b * CC + c) * TT + t0;
                *(short4*)&vt_h[o] = h4;
                *(short4*)&vt_l[o] = l4;
            }
        }
    }
}

// ---- gram (R5, proven): split-bf16 MFMA, LDS-staged. z = b*2 + half.
__global__ __launch_bounds__(256, 4) void gram_mfma(
    const float* __restrict__ pf, const float* __restrict__ ns,
    const int* __restrict__ inxs, const float* __restrict__ v_ns,
    const float* __restrict__ g_ns, float* __restrict__ G, float* __restrict__ S)
{
    __shared__ short Ah[64 * 40], Al[64 * 40], Bh[64 * 40], Bl[64 * 40];
    const int tid = threadIdx.x;
    const int m0 = blockIdx.x * 64, n0 = blockIdx.y * 64;
    const int b = blockIdx.z >> 1, half = blockIdx.z & 1;
    const float* __restrict__ Pb = pf + (size_t)b * TT * CC;
    const float* __restrict__ Nb = ns + (size_t)b * TT * CC;
    const float* __restrict__ Bsrc = half ? Nb : Pb;

    float w0 = 0.f, w1 = 0.f, w2 = 0.f, w3 = 0.f;
    int4 id0 = {0, 0, 0, 0}, id1 = {0, 0, 0, 0};
    if (half) {
        float n2 = v_ns[0]*v_ns[0] + v_ns[1]*v_ns[1] + v_ns[2]*v_ns[2] + v_ns[3]*v_ns[3];
        float sc = g_ns[0] / sqrtf(n2);
        w0 = sc*v_ns[0]; w1 = sc*v_ns[1]; w2 = sc*v_ns[2]; w3 = sc*v_ns[3];
        id0 = *(const int4*)&inxs[(b * TT + m0 + (tid >> 3)) * 4];
        id1 = *(const int4*)&inxs[(b * TT + m0 + 32 + (tid >> 3)) * 4];
    }

    const int lane = tid & 63, wave = tid >> 6;
    const int wm = wave >> 1, wn = wave & 1;
    const int quad = lane >> 4, lr = lane & 15;
    f32x4 z4 = {0.f, 0.f, 0.f, 0.f};
    f32x4 acc[2][2] = {{z4, z4}, {z4, z4}};

    for (int k0 = 0; k0 < CC; k0 += 32) {
        __syncthreads();
        for (int i = 0; i < 2; i++) {
            int flat = i * 256 + tid, r = flat >> 3, q = (flat & 7) * 4;
            float4 a4;
            if (!half) {
                a4 = *(const float4*)&Pb[(m0 + r) * CC + k0 + q];
            } else {
                int4 id = i ? id1 : id0;
                float4 aa = *(const float4*)&Nb[id.x * CC + k0 + q];
                float4 ab = *(const float4*)&Nb[id.y * CC + k0 + q];
                float4 ac = *(const float4*)&Nb[id.z * CC + k0 + q];
                float4 ad = *(const float4*)&Nb[id.w * CC + k0 + q];
                a4.x = w0*aa.x + w1*ab.x + w2*ac.x + w3*ad.x;
                a4.y = w0*aa.y + w1*ab.y + w2*ac.y + w3*ad.y;
                a4.z = w0*aa.z + w1*ab.z + w2*ac.z + w3*ad.z;
                a4.w = w0*aa.w + w1*ab.w + w2*ac.w + w3*ad.w;
            }
            float4 b4 = *(const float4*)&Bsrc[(n0 + r) * CC + k0 + q];
            short4 h4, l4;
            bf_split(a4.x, h4.x, l4.x); bf_split(a4.y, h4.y, l4.y);
            bf_split(a4.z, h4.z, l4.z); bf_split(a4.w, h4.w, l4.w);
            *(short4*)&Ah[r * 40 + q] = h4; *(short4*)&Al[r * 40 + q] = l4;
            bf_split(b4.x, h4.x, l4.x); bf_split(b4.y, h4.y, l4.y);
            bf_split(b4.z, h4.z, l4.z); bf_split(b4.w, h4.w, l4.w);
            *(short4*)&Bh[r * 40 + q] = h4; *(short4*)&Bl[r * 40 + q] = l4;
        }
        __syncthreads();
        bf16x8 bh[2], bl[2];
        for (int tn = 0; tn < 2; tn++) {
            int br = (32 * wn + 16 * tn + lr) * 40 + quad * 8;
            bh[tn] = *(bf16x8*)&Bh[br];
            bl[tn] = *(bf16x8*)&Bl[br];
        }
        for (int tm = 0; tm < 2; tm++) {
            int ar = (32 * wm + 16 * tm + lr) * 40 + quad * 8;
            bf16x8 ah = *(bf16x8*)&Ah[ar];
            bf16x8 al = *(bf16x8*)&Al[ar];
            for (int tn = 0; tn < 2; tn++) {
                acc[tm][tn] = __builtin_amdgcn_mfma_f32_16x16x32_bf16(ah, bh[tn], acc[tm][tn], 0, 0, 0);
                acc[tm][tn] = __builtin_amdgcn_mfma_f32_16x16x32_bf16(ah, bl[tn], acc[tm][tn], 0, 0, 0);
                acc[tm][tn] = __builtin_amdgcn_mfma_f32_16x16x32_bf16(al, bh[tn], acc[tm][tn], 0, 0, 0);
            }
        }
    }
    float* __restrict__ Cb = (half ? S : G) + (size_t)b * TT * TT;
    for (int tm = 0; tm < 2; tm++)
        for (int tn = 0; tn < 2; tn++) {
            int rb = m0 + 32 * wm + 16 * tm + quad * 4;
            int cb = n0 + 32 * wn + 16 * tn + lr;
            for (int reg = 0; reg < 4; reg++)
                Cb[(size_t)(rb + reg) * TT + cb] = acc[tm][tn][reg];
        }
}

// ---- fused: vectorized rowmax conv + S + mask -> softmax -> MFMA PV (vt from L2).
__global__ __launch_bounds__(256, 2) void fused_smax_pv(
    const float* __restrict__ G, const float* __restrict__ S,
    const int* __restrict__ radj, const float* __restrict__ v_pf,
    const float* __restrict__ g_pf,
    const short* __restrict__ vt_h, const short* __restrict__ vt_l,
    float* __restrict__ out)
{
    __shared__ float Gs[20 * 256];
    __shared__ float RM[20 * 256];
    __shared__ short ATH[16 * 264];
    __shared__ short ATL[16 * 264];
    __shared__ float RD[64];
    __shared__ float RMX[64];
    const int tid = threadIdx.x;
    const int xt = blockIdx.x, b = blockIdx.y;
    const int x0 = xt * 16;
    const int rbase = min(max(x0 - 2, 0), TT - 5);
    for (int i = 0; i < 5; i++) {
        int flat = i * 256 + tid, ri = flat >> 6, q = (flat & 63) * 4;
        int r = min(rbase + ri, TT - 1);
        *(float4*)&Gs[ri * 256 + q] = *(const float4*)&G[(size_t)b * TT * TT + r * TT + q];
    }
    float n2 = 0.f;
    for (int i = 0; i < 5; i++) n2 += v_pf[i] * v_pf[i];
    float sc = g_pf[0] / sqrtf(n2);
    float wpf[5];
    for (int i = 0; i < 5; i++) wpf[i] = sc * v_pf[i];
    __syncthreads();
    // windowed row-max, vectorized: 1280 tasks of 4 cols
    for (int t = 0; t < 5; t++) {
        int task = t * 256 + tid;
        int i = task >> 6, g = task & 63;
        const float* row = &Gs[i * 256];
        float4 X = *(float4*)&row[4 * g];
        float m0_, m1_, m2_, m3_;
        if (g == 0) {
            float4 N = *(float4*)&row[4];
            float mx = fmaxf(fmaxf(X.x, X.y), fmaxf(X.z, X.w));
            m0_ = m1_ = m2_ = fmaxf(mx, N.x);
            m3_ = max5(X.y, X.z, X.w, N.x, N.y);
        } else if (g == 63) {
            float4 P = *(float4*)&row[248];
            m0_ = max5(P.z, P.w, X.x, X.y, X.z);
            float mx = fmaxf(fmaxf(X.x, X.y), fmaxf(X.z, X.w));
            m1_ = m2_ = m3_ = fmaxf(P.w, mx);
        } else {
            float4 P = *(float4*)&row[4 * g - 4];
            float4 N = *(float4*)&row[4 * g + 4];
            m0_ = max5(P.z, P.w, X.x, X.y, X.z);
            m1_ = max5(P.w, X.x, X.y, X.z, X.w);
            m2_ = max5(X.x, X.y, X.z, X.w, N.x);
            m3_ = max5(X.y, X.z, X.w, N.x, N.y);
        }
        float4 o4 = {m0_, m1_, m2_, m3_};
        *(float4*)&RM[i * 256 + 4 * g] = o4;
    }
    __syncthreads();
    const int y = tid;
    const size_t sb = (size_t)b * TT * TT;
    float lv[16];
    if (xt > 0 && xt < 15) {
        float rm[20];
        #pragma unroll
        for (int r = 0; r < 20; r++) rm[r] = RM[r * 256 + y];
        #pragma unroll
        for (int xi = 0; xi < 16; xi++) {
            float s = wpf[0] * rm[xi];
            #pragma unroll
            for (int i = 1; i < 5; i++) s = fmaf(wpf[i], rm[xi + i], s);
            lv[xi] = s;
        }
    } else {
        for (int xi = 0; xi < 16; xi++) {
            int sxr = min(max(x0 + xi - 2, 0), TT - 5) - rbase;
            float s = 0.f;
            for (int i = 0; i < 5; i++) s = fmaf(wpf[i], RM[(sxr + i) * 256 + y], s);
            lv[xi] = s;
        }
    }
    for (int xi = 0; xi < 16; xi++) {
        lv[xi] += S[sb + (x0 + xi) * TT + y];
        if (radj[sb + (x0 + xi) * TT + y] == 0) lv[xi] += -1e22f;
    }
    const int lane = tid & 63, wv = tid >> 6;
    for (int xi = 0; xi < 16; xi++) {
        float v = lv[xi];
        for (int o = 32; o; o >>= 1) v = fmaxf(v, __shfl_xor(v, o));
        if (lane == 0) RMX[xi * 4 + wv] = v;
    }
    __syncthreads();
    for (int xi = 0; xi < 16; xi++) {
        float mx = fmaxf(fmaxf(RMX[xi * 4], RMX[xi * 4 + 1]),
                         fmaxf(RMX[xi * 4 + 2], RMX[xi * 4 + 3]));
        float e = __expf(lv[xi] - mx);
        short h, l;
        bf_split(e, h, l);
        ATH[xi * 264 + y] = h;
        ATL[xi * 264 + y] = l;
        for (int o = 32; o; o >>= 1) e += __shfl_xor(e, o);
        if (lane == 0) RD[xi * 4 + wv] = e;
    }
    __syncthreads();
    // PV: out^T[c,q] tiles. A = vt (global split), B = attn (LDS split).
    const int quad = lane >> 4, lr = lane & 15;
    const int c0 = wv * 32;
    const short* __restrict__ vhb = vt_h + (size_t)b * CC * TT;
    const short* __restrict__ vlb = vt_l + (size_t)b * CC * TT;
    const int ar0 = (c0 + lr) * TT, ar1 = ar0 + 16 * TT;
    f32x4 z4 = {0.f, 0.f, 0.f, 0.f};
    f32x4 acc[2] = {z4, z4};
    #pragma unroll
    for (int k0 = 0; k0 < TT; k0 += 32) {
        int ko = k0 + quad * 8;
        bf16x8 bh = *(bf16x8*)&ATH[lr * 264 + ko];
        bf16x8 bl = *(bf16x8*)&ATL[lr * 264 + ko];
        bf16x8 a0h = *(const bf16x8*)&vhb[ar0 + ko];
        bf16x8 a0l = *(const bf16x8*)&vlb[ar0 + ko];
        bf16x8 a1h = *(const bf16x8*)&vhb[ar1 + ko];
        bf16x8 a1l = *(const bf16x8*)&vlb[ar1 + ko];
        acc[0] = __builtin_amdgcn_mfma_f32_16x16x32_bf16(a0h, bh, acc[0], 0, 0, 0);
        acc[0] = __builtin_amdgcn_mfma_f32_16x16x32_bf16(a0h, bl, acc[0], 0, 0, 0);
        acc[0] = __builtin_amdgcn_mfma_f32_16x16x32_bf16(a0l, bh, acc[0], 0, 0, 0);
        acc[1] = __builtin_amdgcn_mfma_f32_16x16x32_bf16(a1h, bh, acc[1], 0, 0, 0);
        acc[1] = __builtin_amdgcn_mfma_f32_16x16x32_bf16(a1h, bl, acc[1], 0, 0, 0);
        acc[1] = __builtin_amdgcn_mfma_f32_16x16x32_bf16(a1l, bh, acc[1], 0, 0, 0);
    }
    float sm = RD[lr * 4] + RD[lr * 4 + 1] + RD[lr * 4 + 2] + RD[lr * 4 + 3];
    float rinv = 1.f / sm;
    for (int tm = 0; tm < 2; tm++) {
        float4 r;
        r.x = acc[tm][0] * rinv; r.y = acc[tm][1] * rinv;
        r.z = acc[tm][2] * rinv; r.w = acc[tm][3] * rinv;
        *(float4*)&out[(size_t)b * TT * CC + (x0 + lr) * CC + c0 + 16 * tm + quad * 4] = r;
    }
}

extern "C" void kernel_launch(void* const* d_in, const int* in_sizes, int n_in,
                              void* d_out, int out_size, void* d_ws, size_t ws_size,
                              hipStream_t stream) {
    const float* x    = (const float*)d_in[0];
    const int*   radj = (const int*)d_in[1];
    const int*   inxs = (const int*)d_in[2];
    const float* Wpf  = (const float*)d_in[3];
    const float* Wns  = (const float*)d_in[4];
    const float* Wv   = (const float*)d_in[5];
    const float* v_pf = (const float*)d_in[6];
    const float* g_pf = (const float*)d_in[7];
    const float* v_ns = (const float*)d_in[8];
    const float* g_ns = (const float*)d_in[9];
    float* out = (float*)d_out;

    char* base = (char*)d_ws;
    float* pf   = (float*)(base);                    // 4MB
    float* ns   = (float*)(base + (4u << 20));       // 4MB
    short* vt_h = (short*)(base + (8u << 20));       // 2MB
    short* vt_l = (short*)(base + (10u << 20));      // 2MB
    float* G    = (float*)(base + (12u << 20));      // 8MB
    float* S    = (float*)(base + (20u << 20));      // 8MB

    proj_kernel<<<dim3(256, 3), 256, 0, stream>>>(x, Wpf, Wns, Wv, pf, ns, vt_h, vt_l);
    gram_mfma<<<dim3(4, 4, 64), 256, 0, stream>>>(pf, ns, inxs, v_ns, g_ns, G, S);
    fused_smax_pv<<<dim3(16, 32), 256, 0, stream>>>(G, S, radj, v_pf, g_pf,
                                                    vt_h, vt_l, out);
}